// Round 9
// baseline (195.410 us; speedup 1.0000x reference)
//
#include <hip/hip_runtime.h>
#include <cstdint>
#include <cstddef>

// Problem dims (fixed by the reference setup_inputs):
#define B_DIM   8192
#define IN_DIM  1024
#define OUT_DIM 4096
#define KT2     (IN_DIM / 64)    // 16 panels (of K=64) per 32-row tile

typedef __attribute__((ext_vector_type(8)))  int   i32x8;   // fp8 MFMA A/B frag (32 B)
typedef __attribute__((ext_vector_type(4)))  int   i32x4;
typedef __attribute__((ext_vector_type(16))) float f32x16;  // 32x32 MFMA accumulator

// async global->LDS DMA, 16B per lane. LDS dest is wave-uniform base + lane*16.
__device__ __forceinline__ void async_copy16(const void* gptr, void* ldsptr) {
    __builtin_amdgcn_global_load_lds(
        (__attribute__((address_space(1))) void*)gptr,
        (__attribute__((address_space(3))) void*)ldsptr,
        16, 0, 0);
}

// pack 4 fp32 -> 4 OCP e4m3 bytes (little-endian k order)
__device__ __forceinline__ int pack4_fp8(float a, float b, float c, float d) {
    int pk = __builtin_amdgcn_cvt_pk_fp8_f32(a, b, 0, false);   // bytes 0-1
    pk = __builtin_amdgcn_cvt_pk_fp8_f32(c, d, pk, true);       // bytes 2-3
    return pk;
}

// fp8 panel: 32 rows x 64 k = 2048 B. Lane l owns row m=l&31, k=(l>>5)*32+[0,32).
// Half h (k-bytes [h*16,h*16+16)) lives at panel + h*1024 + l*16: staging is two
// fully-linear global_load_lds (A) or two dwordx4 reg-loads (B), frag reads two
// ds_read_b128 at base + lane*16 (conflict-free).

// ---------------------------------------------------------------------------
// Kernel 1 (merged quantizer): 1024 blocks x 256 threads (~4 blocks/CU).
//  b < 512 : X-quant. mt = b>>1 (32 rows), kh = b&1 (k-half). Wave w emits
//            panels kt2 = kh*8 + w*2 + {0,1}; xsq partial -> xsq2[kh][m].
//  b >= 512: W-quant. nt = (b-512)&127, q = (b-512)>>7 (k-quarter). LDS
//            transpose, wave w emits panel kt2 = q*4+w; partial -> wsq2[q][n].
// All norm outputs are PURE STORES (no atomics, no zero-fill, no cross-block
// ordering) — partials are summed in the GEMM epilogue.
// ---------------------------------------------------------------------------
__global__ __launch_bounds__(256) void quant_kernel(
    const float* __restrict__ x, const float* __restrict__ wgt,
    unsigned char* __restrict__ At, unsigned char* __restrict__ Bt,
    float* __restrict__ xsq2,     // [2][B_DIM]
    float* __restrict__ wsq2)     // [4][OUT_DIM]
{
    __shared__ float tile[256 * 33];      // W-path transpose tile ([k][n], pad 33)
    __shared__ float red[4][32];

    const int t = threadIdx.x;
    const int w = t >> 6;                 // 0..3
    const int l = t & 63;
    const int b = blockIdx.x;

    if (b < 512) {
        // ---- X-quant ----
        const int mt = b >> 1, kh = b & 1;
        const int m  = mt * 32 + (l & 31);
        float s = 0.0f;
        #pragma unroll
        for (int p = 0; p < 2; ++p) {
            const int kt2 = kh * 8 + w * 2 + p;
            const float* src = x + (size_t)m * IN_DIM + kt2 * 64 + (l >> 5) * 32;
            i32x4 lo, hi;
            #pragma unroll
            for (int j = 0; j < 4; ++j) {
                float4 v = ((const float4*)src)[j];
                s += v.x*v.x + v.y*v.y + v.z*v.z + v.w*v.w;
                lo[j] = pack4_fp8(v.x, v.y, v.z, v.w);
            }
            #pragma unroll
            for (int j = 0; j < 4; ++j) {
                float4 v = ((const float4*)src)[4 + j];
                s += v.x*v.x + v.y*v.y + v.z*v.z + v.w*v.w;
                hi[j] = pack4_fp8(v.x, v.y, v.z, v.w);
            }
            unsigned char* pan = At + ((size_t)mt * KT2 + kt2) * 2048;
            *(i32x4*)(pan + l * 16)        = lo;
            *(i32x4*)(pan + 1024 + l * 16) = hi;
        }
        s += __shfl_down(s, 32, 64);      // lanes l, l+32 = same row's k-slices
        if (l < 32) red[w][l] = s;
        __syncthreads();
        if (t < 32)
            xsq2[kh * B_DIM + mt * 32 + t] =
                red[0][t] + red[1][t] + red[2][t] + red[3][t];
    } else {
        // ---- W-quant ----
        const int idx = b - 512;
        const int nt = idx & 127, q = idx >> 7, n0 = nt * 32;

        const int rbase = t >> 2, cg = (t & 3) * 8;
        #pragma unroll
        for (int rep = 0; rep < 4; ++rep) {
            const int r = rbase + rep * 64;
            const float* src = wgt + (size_t)(q * 256 + r) * OUT_DIM + n0 + cg;
            float4 v0 = ((const float4*)src)[0];
            float4 v1 = ((const float4*)src)[1];
            float* d = &tile[r * 33 + cg];
            d[0] = v0.x; d[1] = v0.y; d[2] = v0.z; d[3] = v0.w;
            d[4] = v1.x; d[5] = v1.y; d[6] = v1.z; d[7] = v1.w;
        }
        __syncthreads();

        const int kt2 = q * 4 + w;
        const int n   = l & 31;
        const int kb  = w * 64 + (l >> 5) * 32;
        float s = 0.0f;
        i32x4 lo, hi;
        #pragma unroll
        for (int j4 = 0; j4 < 4; ++j4) {
            float f0 = tile[(kb + j4 * 4 + 0) * 33 + n];
            float f1 = tile[(kb + j4 * 4 + 1) * 33 + n];
            float f2 = tile[(kb + j4 * 4 + 2) * 33 + n];
            float f3 = tile[(kb + j4 * 4 + 3) * 33 + n];
            s += f0*f0 + f1*f1 + f2*f2 + f3*f3;
            lo[j4] = pack4_fp8(f0, f1, f2, f3);
        }
        #pragma unroll
        for (int j4 = 0; j4 < 4; ++j4) {
            float f0 = tile[(kb + 16 + j4 * 4 + 0) * 33 + n];
            float f1 = tile[(kb + 16 + j4 * 4 + 1) * 33 + n];
            float f2 = tile[(kb + 16 + j4 * 4 + 2) * 33 + n];
            float f3 = tile[(kb + 16 + j4 * 4 + 3) * 33 + n];
            s += f0*f0 + f1*f1 + f2*f2 + f3*f3;
            hi[j4] = pack4_fp8(f0, f1, f2, f3);
        }
        unsigned char* pan = Bt + ((size_t)nt * KT2 + kt2) * 2048;
        *(i32x4*)(pan + l * 16)        = lo;
        *(i32x4*)(pan + 1024 + l * 16) = hi;

        s += __shfl_down(s, 32, 64);      // combine k-halves of same n
        if (l < 32) red[w][l] = s;
        __syncthreads();
        if (t < 32)
            wsq2[q * OUT_DIM + n0 + t] =
                red[0][t] + red[1][t] + red[2][t] + red[3][t];
    }
}

// ---------------------------------------------------------------------------
// Kernel 2: MX-fp8 GEMM. 128x256 tile, 4 waves, each 128x64 = 4x2 frags of
// mfma_scale_f32_32x32x64. A: LDS 3-buf (4-wave shared, 2-deep DMA prefetch).
// B: REGISTER double-buffer straight from global (zero cross-wave reuse ->
// LDS round-trip was pure waste: -16 KB/step DMA, -2/3 ds_reads, no lgkm dep).
// In-order vmcnt: step k issues [B(k+1) x4, A-DMA(k+2) x2]; top-of-step
// outstanding = [A(k),B(k),A(k+1)] -> vmcnt(2) retires exactly A(k)+B(k)
// (A(k) is strictly oldest under any intra-step reorder; B is additionally
// compiler-tracked as a register data-dependency). 24 KB LDS -> 2 blocks/CU.
// setprio (T5), counted vmcnt (T4). K-loop fully unrolled (static breg
// indices — rule #20). Epilogue fuses norms.
// ---------------------------------------------------------------------------
__global__ __launch_bounds__(256, 2) void rbf_gemm_kernel(
    const unsigned char* __restrict__ At,   // [256*KT2][2048]
    const unsigned char* __restrict__ Bt,   // [128*KT2][2048]
    const float* __restrict__ xsq2,         // [2][B_DIM]
    const float* __restrict__ wsq2,         // [4][OUT_DIM]
    float* __restrict__ out)
{
    __shared__ __align__(16) unsigned char sm[3][8192];   // A panels only, 3-buf

    const int t    = threadIdx.x;
    const int w    = t >> 6;              // 0..3 (waveCol)
    const int l    = t & 63;
    const int l32  = l & 31;
    const int half = l >> 5;

    // L2-blocked XCD swizzle (bijective), as r7.
    const int wg  = blockIdx.y * 64 + blockIdx.x;   // 0..1023
    const int x8  = wg & 7;
    const int i   = wg >> 3;
    const int bng = i >> 5;
    const int bmi = (i >> 2) & 7;
    const int bm  = x8 * 8 + bmi;         // 0..63
    const int bn  = bng * 4 + (i & 3);    // 0..15

    f32x16 acc[4][2];
    #pragma unroll
    for (int mi = 0; mi < 4; ++mi)
        #pragma unroll
        for (int ni = 0; ni < 2; ++ni)
            #pragma unroll
            for (int r = 0; r < 16; ++r)
                acc[mi][ni][r] = 0.0f;

    const unsigned char* gaBase  = At + (size_t)(bm * 4 + w)     * (KT2 * 2048);
    const unsigned char* gbBase0 = Bt + (size_t)(bn * 8 + w * 2) * (KT2 * 2048);
    const unsigned char* gbBase1 = gbBase0 + (size_t)(KT2 * 2048);

    // B register double-buffer: [slot][frag][lo/hi] as i32x4 pairs.
    i32x4 bq[2][2][2];

    auto stageA = [&](int buf, int k) {              // 2 DMAs (wave's own panel w)
        const unsigned char* ga = gaBase + k * 2048;
        unsigned char* As = (unsigned char*)sm + buf * 8192 + w * 2048;
        async_copy16(ga + l * 16,        As);
        async_copy16(ga + 1024 + l * 16, As + 1024);
    };

    auto ldfragA = [&](const unsigned char* base, int p) -> i32x8 {
        i32x4 lo = *(const i32x4*)(base + p * 2048 + l * 16);
        i32x4 hi = *(const i32x4*)(base + p * 2048 + 1024 + l * 16);
        i32x8 r;
        r[0] = lo[0]; r[1] = lo[1]; r[2] = lo[2]; r[3] = lo[3];
        r[4] = hi[0]; r[5] = hi[1]; r[6] = hi[2]; r[7] = hi[3];
        return r;
    };

    // Prologue issue order matters for in-order vmcnt: [A0(2), B0(4), A1(2)].
    stageA(0, 0);
    {
        const unsigned char* g0 = gbBase0;
        const unsigned char* g1 = gbBase1;
        bq[0][0][0] = *(const i32x4*)(g0 + l * 16);
        bq[0][0][1] = *(const i32x4*)(g0 + 1024 + l * 16);
        bq[0][1][0] = *(const i32x4*)(g1 + l * 16);
        bq[0][1][1] = *(const i32x4*)(g1 + 1024 + l * 16);
    }
    stageA(1, 1);

    #pragma unroll
    for (int k = 0; k < 16; ++k) {
        // outstanding (oldest first): A(k) 2, B(k) 4, A(k+1) 2  -> vmcnt(2)
        // retires A(k)+B(k), keeps A(k+1) in flight. Last iter drains all.
        if (k < 15) asm volatile("s_waitcnt vmcnt(2)" ::: "memory");
        else        asm volatile("s_waitcnt vmcnt(0)" ::: "memory");
        __builtin_amdgcn_s_barrier();              // all waves' A(k) panels landed
        __builtin_amdgcn_sched_barrier(0);         // no ds_read hoists above

        // Issue next-step B (slot (k+1)&1: disjoint from this step's (k&1)),
        // then next-next A DMA (3-buf WAR-safe: barrier above orders readers).
        if (k <= 14) {
            const int slot = (k + 1) & 1;
            const unsigned char* g0 = gbBase0 + (k + 1) * 2048;
            const unsigned char* g1 = gbBase1 + (k + 1) * 2048;
            bq[slot][0][0] = *(const i32x4*)(g0 + l * 16);
            bq[slot][0][1] = *(const i32x4*)(g0 + 1024 + l * 16);
            bq[slot][1][0] = *(const i32x4*)(g1 + l * 16);
            bq[slot][1][1] = *(const i32x4*)(g1 + 1024 + l * 16);
        }
        if (k <= 13) stageA((k + 2) % 3, k + 2);

        const unsigned char* As = (const unsigned char*)sm + (k % 3) * 8192;
        i32x8 af[4];
        #pragma unroll
        for (int mi = 0; mi < 4; ++mi)
            af[mi] = ldfragA(As, mi);

        const int cs = k & 1;
        i32x8 bf0, bf1;
        #pragma unroll
        for (int j = 0; j < 4; ++j) {
            bf0[j]     = bq[cs][0][0][j];
            bf0[4 + j] = bq[cs][0][1][j];
            bf1[j]     = bq[cs][1][0][j];
            bf1[4 + j] = bq[cs][1][1][j];
        }

        __builtin_amdgcn_s_setprio(1);
        #pragma unroll
        for (int mi = 0; mi < 4; ++mi) {
            acc[mi][0] = __builtin_amdgcn_mfma_scale_f32_32x32x64_f8f6f4(
                af[mi], bf0, acc[mi][0],
                0, 0,                 // cbsz=fp8(e4m3), blgp=fp8(e4m3)
                0, 0x7F7F7F7F,        // A scales = 1.0 (E8M0 127)
                0, 0x7F7F7F7F);       // B scales = 1.0
            acc[mi][1] = __builtin_amdgcn_mfma_scale_f32_32x32x64_f8f6f4(
                af[mi], bf1, acc[mi][1],
                0, 0, 0, 0x7F7F7F7F, 0, 0x7F7F7F7F);
        }
        __builtin_amdgcn_s_setprio(0);
    }

    // Epilogue. 32x32 C/D layout: col(n)=lane&31, row(m)=(r&3)+8*(r>>2)+4*(l>>5).
    const int ncol = bn * 256 + w * 64 + l32;
    const float wsn0 = wsq2[ncol]      + wsq2[OUT_DIM + ncol]
                     + wsq2[2 * OUT_DIM + ncol]      + wsq2[3 * OUT_DIM + ncol];
    const float wsn1 = wsq2[ncol + 32] + wsq2[OUT_DIM + ncol + 32]
                     + wsq2[2 * OUT_DIM + ncol + 32] + wsq2[3 * OUT_DIM + ncol + 32];
    #pragma unroll
    for (int mi = 0; mi < 4; ++mi) {
        const int mbase = bm * 128 + mi * 32 + 4 * half;
        #pragma unroll
        for (int r2 = 0; r2 < 4; ++r2) {
            #pragma unroll
            for (int r1 = 0; r1 < 4; ++r1) {
                const int m  = mbase + r1 + 8 * r2;
                const float xs = xsq2[m] + xsq2[B_DIM + m];
                float* orow = out + (size_t)m * OUT_DIM + ncol;
                orow[0]  = xs + wsn0 - 2.0f * acc[mi][0][r2 * 4 + r1];
                orow[32] = xs + wsn1 - 2.0f * acc[mi][1][r2 * 4 + r1];
            }
        }
    }
}

// ---------------------------------------------------------------------------
extern "C" void kernel_launch(void* const* d_in, const int* in_sizes, int n_in,
                              void* d_out, int out_size, void* d_ws, size_t ws_size,
                              hipStream_t stream)
{
    const float* x   = (const float*)d_in[0];   // (8192, 1024) fp32
    const float* wgt = (const float*)d_in[1];   // (1024, 4096) fp32
    float* out = (float*)d_out;                 // (8192, 4096) fp32
    char*  ws  = (char*)d_ws;

    // workspace: At (8 MB) | Bt (4 MB) | xsq2 (64 KB) | wsq2 (64 KB)
    unsigned char* At = (unsigned char*)ws;
    unsigned char* Bt = (unsigned char*)(ws + (size_t)B_DIM * IN_DIM);
    float* xsq2 = (float*)(ws + (size_t)B_DIM * IN_DIM + (size_t)OUT_DIM * IN_DIM);
    float* wsq2 = xsq2 + 2 * B_DIM;

    quant_kernel<<<1024, 256, 0, stream>>>(x, wgt, At, Bt, xsq2, wsq2);
    rbf_gemm_kernel<<<dim3(64, 16), 256, 0, stream>>>(At, Bt, xsq2, wsq2, out);
}

// Round 10
// 190.267 us; speedup vs baseline: 1.0270x; 1.0270x over previous
//
#include <hip/hip_runtime.h>
#include <cstdint>
#include <cstddef>

// Problem dims (fixed by the reference setup_inputs):
#define B_DIM   8192
#define IN_DIM  1024
#define OUT_DIM 4096
#define KT2     (IN_DIM / 64)    // 16 panels (of K=64) per 32-row tile

typedef __attribute__((ext_vector_type(8)))  int   i32x8;   // fp8 MFMA A/B frag (32 B)
typedef __attribute__((ext_vector_type(4)))  int   i32x4;
typedef __attribute__((ext_vector_type(16))) float f32x16;  // 32x32 MFMA accumulator

// async global->LDS DMA, 16B per lane. LDS dest is wave-uniform base + lane*16.
__device__ __forceinline__ void async_copy16(const void* gptr, void* ldsptr) {
    __builtin_amdgcn_global_load_lds(
        (__attribute__((address_space(1))) void*)gptr,
        (__attribute__((address_space(3))) void*)ldsptr,
        16, 0, 0);
}

// pack 4 fp32 -> 4 OCP e4m3 bytes (little-endian k order)
__device__ __forceinline__ int pack4_fp8(float a, float b, float c, float d) {
    int pk = __builtin_amdgcn_cvt_pk_fp8_f32(a, b, 0, false);   // bytes 0-1
    pk = __builtin_amdgcn_cvt_pk_fp8_f32(c, d, pk, true);       // bytes 2-3
    return pk;
}

// fp8 panel: 32 rows x 64 k = 2048 B. Lane l owns row m=l&31, k=(l>>5)*32+[0,32).
// Half h (k-bytes [h*16,h*16+16)) lives at panel + h*1024 + l*16: staging is two
// fully-linear global_load_lds (A) or two dwordx4 reg-loads (B), frag reads two
// ds_read_b128 at base + lane*16 (conflict-free).

// ---------------------------------------------------------------------------
// Kernel 1 (merged quantizer): 1024 blocks x 256 threads (~4 blocks/CU).
//  b < 512 : X-quant. mt = b>>1 (32 rows), kh = b&1 (k-half). Wave w emits
//            panels kt2 = kh*8 + w*2 + {0,1}; xsq partial -> xsq2[kh][m].
//  b >= 512: W-quant. nt = (b-512)&127, q = (b-512)>>7 (k-quarter). LDS
//            transpose, wave w emits panel kt2 = q*4+w; partial -> wsq2[q][n].
// All norm outputs are PURE STORES (no atomics, no zero-fill, no cross-block
// ordering) — partials are summed in the GEMM epilogue.
// ---------------------------------------------------------------------------
__global__ __launch_bounds__(256) void quant_kernel(
    const float* __restrict__ x, const float* __restrict__ wgt,
    unsigned char* __restrict__ At, unsigned char* __restrict__ Bt,
    float* __restrict__ xsq2,     // [2][B_DIM]
    float* __restrict__ wsq2)     // [4][OUT_DIM]
{
    __shared__ float tile[256 * 33];      // W-path transpose tile ([k][n], pad 33)
    __shared__ float red[4][32];

    const int t = threadIdx.x;
    const int w = t >> 6;                 // 0..3
    const int l = t & 63;
    const int b = blockIdx.x;

    if (b < 512) {
        // ---- X-quant ----
        const int mt = b >> 1, kh = b & 1;
        const int m  = mt * 32 + (l & 31);
        float s = 0.0f;
        #pragma unroll
        for (int p = 0; p < 2; ++p) {
            const int kt2 = kh * 8 + w * 2 + p;
            const float* src = x + (size_t)m * IN_DIM + kt2 * 64 + (l >> 5) * 32;
            i32x4 lo, hi;
            #pragma unroll
            for (int j = 0; j < 4; ++j) {
                float4 v = ((const float4*)src)[j];
                s += v.x*v.x + v.y*v.y + v.z*v.z + v.w*v.w;
                lo[j] = pack4_fp8(v.x, v.y, v.z, v.w);
            }
            #pragma unroll
            for (int j = 0; j < 4; ++j) {
                float4 v = ((const float4*)src)[4 + j];
                s += v.x*v.x + v.y*v.y + v.z*v.z + v.w*v.w;
                hi[j] = pack4_fp8(v.x, v.y, v.z, v.w);
            }
            unsigned char* pan = At + ((size_t)mt * KT2 + kt2) * 2048;
            *(i32x4*)(pan + l * 16)        = lo;
            *(i32x4*)(pan + 1024 + l * 16) = hi;
        }
        s += __shfl_down(s, 32, 64);      // lanes l, l+32 = same row's k-slices
        if (l < 32) red[w][l] = s;
        __syncthreads();
        if (t < 32)
            xsq2[kh * B_DIM + mt * 32 + t] =
                red[0][t] + red[1][t] + red[2][t] + red[3][t];
    } else {
        // ---- W-quant ----
        const int idx = b - 512;
        const int nt = idx & 127, q = idx >> 7, n0 = nt * 32;

        const int rbase = t >> 2, cg = (t & 3) * 8;
        #pragma unroll
        for (int rep = 0; rep < 4; ++rep) {
            const int r = rbase + rep * 64;
            const float* src = wgt + (size_t)(q * 256 + r) * OUT_DIM + n0 + cg;
            float4 v0 = ((const float4*)src)[0];
            float4 v1 = ((const float4*)src)[1];
            float* d = &tile[r * 33 + cg];
            d[0] = v0.x; d[1] = v0.y; d[2] = v0.z; d[3] = v0.w;
            d[4] = v1.x; d[5] = v1.y; d[6] = v1.z; d[7] = v1.w;
        }
        __syncthreads();

        const int kt2 = q * 4 + w;
        const int n   = l & 31;
        const int kb  = w * 64 + (l >> 5) * 32;
        float s = 0.0f;
        i32x4 lo, hi;
        #pragma unroll
        for (int j4 = 0; j4 < 4; ++j4) {
            float f0 = tile[(kb + j4 * 4 + 0) * 33 + n];
            float f1 = tile[(kb + j4 * 4 + 1) * 33 + n];
            float f2 = tile[(kb + j4 * 4 + 2) * 33 + n];
            float f3 = tile[(kb + j4 * 4 + 3) * 33 + n];
            s += f0*f0 + f1*f1 + f2*f2 + f3*f3;
            lo[j4] = pack4_fp8(f0, f1, f2, f3);
        }
        #pragma unroll
        for (int j4 = 0; j4 < 4; ++j4) {
            float f0 = tile[(kb + 16 + j4 * 4 + 0) * 33 + n];
            float f1 = tile[(kb + 16 + j4 * 4 + 1) * 33 + n];
            float f2 = tile[(kb + 16 + j4 * 4 + 2) * 33 + n];
            float f3 = tile[(kb + 16 + j4 * 4 + 3) * 33 + n];
            s += f0*f0 + f1*f1 + f2*f2 + f3*f3;
            hi[j4] = pack4_fp8(f0, f1, f2, f3);
        }
        unsigned char* pan = Bt + ((size_t)nt * KT2 + kt2) * 2048;
        *(i32x4*)(pan + l * 16)        = lo;
        *(i32x4*)(pan + 1024 + l * 16) = hi;

        s += __shfl_down(s, 32, 64);      // combine k-halves of same n
        if (l < 32) red[w][l] = s;
        __syncthreads();
        if (t < 32)
            wsq2[q * OUT_DIM + n0 + t] =
                red[0][t] + red[1][t] + red[2][t] + red[3][t];
    }
}

// ---------------------------------------------------------------------------
// Kernel 2: MX-fp8 GEMM, write-stream smoothing. 128x128 tile, grid 2048,
// __launch_bounds__(256,4) -> 4 blocks/CU resident: epilogue store bursts are
// half-sized and 4-deep staggered, so each hides under 3 other blocks'
// K-loops (GEMM is WRITE-dominated: ~174 MB HBM ~= 27.6 us floor > 14.7 us
// MFMA). Per wave: 128x32 output = 4x1 frags. A: LDS 3-buf (24 KB, 4-wave
// shared). B: register double-buffer (2 dwordx4/step). In-order vmcnt:
// prologue [A0(2),B0(2),A1(2)]; step k issues [B(k+1) x2, A(k+2) x2];
// top-of-step outstanding = [A(k),B(k),A(k+1)] -> vmcnt(2) retires A(k)+B(k).
// setprio (T5), counted vmcnt (T4), bijective XCD/L2-blocked swizzle (T1).
// ---------------------------------------------------------------------------
__global__ __launch_bounds__(256, 4) void rbf_gemm_kernel(
    const unsigned char* __restrict__ At,   // [256*KT2][2048]
    const unsigned char* __restrict__ Bt,   // [128*KT2][2048]
    const float* __restrict__ xsq2,         // [2][B_DIM]
    const float* __restrict__ wsq2,         // [4][OUT_DIM]
    float* __restrict__ out)
{
    __shared__ __align__(16) unsigned char sm[3][8192];   // A panels only, 3-buf

    const int t    = threadIdx.x;
    const int w    = t >> 6;              // 0..3
    const int l    = t & 63;
    const int l32  = l & 31;
    const int half = l >> 5;

    // Bijective XCD/L2-blocked swizzle (2048 % 8 == 0). XCD x owns bm in
    // [x*8, x*8+8) (A slice 1 MB, L2-resident); bn iterated in groups of 8
    // (live B slice 2 MB). Order per XCD: bng -> bmi -> bn-in-group.
    const int wg  = blockIdx.y * 64 + blockIdx.x;   // 0..2047
    const int x8  = wg & 7;
    const int i   = wg >> 3;              // 0..255
    const int bng = i >> 6;               // 0..3
    const int bmi = (i >> 3) & 7;         // 0..7
    const int bm  = x8 * 8 + bmi;         // 0..63
    const int bn  = bng * 8 + (i & 7);    // 0..31

    f32x16 acc[4];
    #pragma unroll
    for (int mi = 0; mi < 4; ++mi)
        #pragma unroll
        for (int r = 0; r < 16; ++r)
            acc[mi][r] = 0.0f;

    const unsigned char* gaBase = At + (size_t)(bm * 4 + w) * (KT2 * 2048);
    const unsigned char* gbBase = Bt + (size_t)(bn * 4 + w) * (KT2 * 2048);

    // B register double-buffer: [slot][lo/hi] as i32x4 pairs.
    i32x4 bq[2][2];

    auto stageA = [&](int buf, int k) {              // 2 DMAs (wave's own panel w)
        const unsigned char* ga = gaBase + k * 2048;
        unsigned char* As = (unsigned char*)sm + buf * 8192 + w * 2048;
        async_copy16(ga + l * 16,        As);
        async_copy16(ga + 1024 + l * 16, As + 1024);
    };

    auto ldfragA = [&](const unsigned char* base, int p) -> i32x8 {
        i32x4 lo = *(const i32x4*)(base + p * 2048 + l * 16);
        i32x4 hi = *(const i32x4*)(base + p * 2048 + 1024 + l * 16);
        i32x8 r;
        r[0] = lo[0]; r[1] = lo[1]; r[2] = lo[2]; r[3] = lo[3];
        r[4] = hi[0]; r[5] = hi[1]; r[6] = hi[2]; r[7] = hi[3];
        return r;
    };

    // Prologue issue order matters for in-order vmcnt: [A0(2), B0(2), A1(2)].
    stageA(0, 0);
    bq[0][0] = *(const i32x4*)(gbBase + l * 16);
    bq[0][1] = *(const i32x4*)(gbBase + 1024 + l * 16);
    stageA(1, 1);

    #pragma unroll
    for (int k = 0; k < 16; ++k) {
        // outstanding (oldest first): A(k) 2, B(k) 2, A(k+1) 2 -> vmcnt(2)
        // retires A(k)+B(k), keeps A(k+1) in flight. Last iter drains all.
        if (k < 15) asm volatile("s_waitcnt vmcnt(2)" ::: "memory");
        else        asm volatile("s_waitcnt vmcnt(0)" ::: "memory");
        __builtin_amdgcn_s_barrier();              // all waves' A(k) panel landed
        __builtin_amdgcn_sched_barrier(0);         // no ds_read hoists above

        // Issue next-step B (slot (k+1)&1, disjoint from in-use k&1), then
        // next-next A DMA (3-buf WAR-safe: barrier above orders readers).
        if (k <= 14) {
            const int slot = (k + 1) & 1;
            const unsigned char* g = gbBase + (k + 1) * 2048;
            bq[slot][0] = *(const i32x4*)(g + l * 16);
            bq[slot][1] = *(const i32x4*)(g + 1024 + l * 16);
        }
        if (k <= 13) stageA((k + 2) % 3, k + 2);

        const unsigned char* As = (const unsigned char*)sm + (k % 3) * 8192;
        i32x8 af[4];
        #pragma unroll
        for (int mi = 0; mi < 4; ++mi)
            af[mi] = ldfragA(As, mi);

        const int cs = k & 1;
        i32x8 bf;
        #pragma unroll
        for (int j = 0; j < 4; ++j) {
            bf[j]     = bq[cs][0][j];
            bf[4 + j] = bq[cs][1][j];
        }

        __builtin_amdgcn_s_setprio(1);
        #pragma unroll
        for (int mi = 0; mi < 4; ++mi)
            acc[mi] = __builtin_amdgcn_mfma_scale_f32_32x32x64_f8f6f4(
                af[mi], bf, acc[mi],
                0, 0,                 // cbsz=fp8(e4m3), blgp=fp8(e4m3)
                0, 0x7F7F7F7F,        // A scales = 1.0 (E8M0 127)
                0, 0x7F7F7F7F);       // B scales = 1.0
        __builtin_amdgcn_s_setprio(0);
    }

    // Epilogue. 32x32 C/D layout: col(n)=lane&31, row(m)=(r&3)+8*(r>>2)+4*(l>>5).
    const int ncol = bn * 128 + w * 32 + l32;
    const float wsn = wsq2[ncol]               + wsq2[OUT_DIM + ncol]
                    + wsq2[2 * OUT_DIM + ncol] + wsq2[3 * OUT_DIM + ncol];
    #pragma unroll
    for (int mi = 0; mi < 4; ++mi) {
        const int mbase = bm * 128 + mi * 32 + 4 * half;
        #pragma unroll
        for (int r2 = 0; r2 < 4; ++r2) {
            #pragma unroll
            for (int r1 = 0; r1 < 4; ++r1) {
                const int m  = mbase + r1 + 8 * r2;
                const float xs = xsq2[m] + xsq2[B_DIM + m];
                out[(size_t)m * OUT_DIM + ncol] =
                    xs + wsn - 2.0f * acc[mi][r2 * 4 + r1];
            }
        }
    }
}

// ---------------------------------------------------------------------------
extern "C" void kernel_launch(void* const* d_in, const int* in_sizes, int n_in,
                              void* d_out, int out_size, void* d_ws, size_t ws_size,
                              hipStream_t stream)
{
    const float* x   = (const float*)d_in[0];   // (8192, 1024) fp32
    const float* wgt = (const float*)d_in[1];   // (1024, 4096) fp32
    float* out = (float*)d_out;                 // (8192, 4096) fp32
    char*  ws  = (char*)d_ws;

    // workspace: At (8 MB) | Bt (4 MB) | xsq2 (64 KB) | wsq2 (64 KB)
    unsigned char* At = (unsigned char*)ws;
    unsigned char* Bt = (unsigned char*)(ws + (size_t)B_DIM * IN_DIM);
    float* xsq2 = (float*)(ws + (size_t)B_DIM * IN_DIM + (size_t)OUT_DIM * IN_DIM);
    float* wsq2 = xsq2 + 2 * B_DIM;

    quant_kernel<<<1024, 256, 0, stream>>>(x, wgt, At, Bt, xsq2, wsq2);
    rbf_gemm_kernel<<<dim3(64, 32), 256, 0, stream>>>(At, Bt, xsq2, wsq2, out);
}